// Round 8
// baseline (849.372 us; speedup 1.0000x reference)
//
#include <hip/hip_runtime.h>
#include <cstdint>
#include <cstddef>

// Problem constants (ViTDet block, B=4, 64x64, DIM=768, 14x14 windows)
#define NIMG   4
#define GRIDSZ 64          // H = W = 64
#define CH     768
#define NHEAD  12
#define WSZ    14
#define NWINS  100         // 4 images * 5*5 windows
#define NTOK   196         // 14*14
#define MWIN   19600       // NWINS*NTOK
#define MREAL  16384       // 4*64*64
#define MLPC   3072
#define QKSCALE 0.125f

#define KSTR 72            // Ks LDS row stride (u16)
#define VSTR 216           // Vt row stride (u16)
#define PSTR 40            // P slice row stride (u16)

typedef unsigned short u16;
typedef __attribute__((ext_vector_type(8))) short bf16x8;
typedef __attribute__((ext_vector_type(4))) float f32x4;

__device__ __forceinline__ float b2f(u16 u) {
  uint32_t x = (uint32_t)u << 16; float f; __builtin_memcpy(&f, &x, 4); return f;
}
__device__ __forceinline__ u16 f2b(float f) {
  uint32_t x; __builtin_memcpy(&x, &f, 4);
  x += 0x7fffu + ((x >> 16) & 1u);           // round-to-nearest-even
  return (u16)(x >> 16);
}

// Fast exact-GELU: erf via Abramowitz-Stegun 7.1.26 (|err| <= 1.5e-7).
__device__ __forceinline__ float fast_gelu(float x) {
  float z  = x * 0.70710678118654752440f;
  float az = fabsf(z);
  float t  = 1.0f / (1.0f + 0.3275911f * az);
  float poly = ((((1.061405429f * t - 1.453152027f) * t + 1.421413741f) * t
                 - 0.284496736f) * t + 0.254829592f) * t;
  float e  = __expf(-az * az);
  float erfv = copysignf(1.0f - poly * e, z);
  return 0.5f * x * (1.0f + erfv);
}

// async global->LDS, 16B per lane; lds base must be wave-uniform
__device__ __forceinline__ void gl_lds16(const u16* g, u16* l) {
  __builtin_amdgcn_global_load_lds(
      (const __attribute__((address_space(1))) unsigned int*)g,
      (__attribute__((address_space(3))) unsigned int*)l, 16, 0, 0);
}

// ---------------------------------------------------------------------------
// Transpose NCHW -> NHWC  (f32 -> f32), 32x32 LDS tiles
// ---------------------------------------------------------------------------
__global__ __launch_bounds__(256) void k_nchw2nhwc(const float* __restrict__ in,
                                                   float* __restrict__ out) {
  __shared__ float tile[32][33];
  int b  = blockIdx.z;
  int g0 = blockIdx.x * 32;
  int c0 = blockIdx.y * 32;
  int tx = threadIdx.x, ty = threadIdx.y;  // 32 x 8
  const float* ip = in + (size_t)b * CH * 4096;
  float* op = out + (size_t)b * 4096 * CH;
#pragma unroll
  for (int k = 0; k < 32; k += 8)
    tile[ty + k][tx] = ip[(size_t)(c0 + ty + k) * 4096 + g0 + tx];
  __syncthreads();
#pragma unroll
  for (int k = 0; k < 32; k += 8)
    op[(size_t)(g0 + ty + k) * CH + c0 + tx] = tile[tx][ty + k];
}

__global__ __launch_bounds__(256) void k_nhwc2nchw(const float* __restrict__ in,
                                                   float* __restrict__ out) {
  __shared__ float tile[32][33];
  int b  = blockIdx.z;
  int g0 = blockIdx.x * 32;
  int c0 = blockIdx.y * 32;
  int tx = threadIdx.x, ty = threadIdx.y;
  const float* ip = in + (size_t)b * 4096 * CH;
  float* op = out + (size_t)b * CH * 4096;
#pragma unroll
  for (int k = 0; k < 32; k += 8)
    tile[ty + k][tx] = ip[(size_t)(g0 + ty + k) * CH + c0 + tx];
  __syncthreads();
#pragma unroll
  for (int k = 0; k < 32; k += 8)
    op[(size_t)(c0 + ty + k) * 4096 + g0 + tx] = tile[tx][ty + k];
}

// ---------------------------------------------------------------------------
// Weight convert+transpose: in f32 [K][N] -> out bf16 [N][K]
// ---------------------------------------------------------------------------
__global__ __launch_bounds__(256) void k_wt(const float* __restrict__ in,
                                            u16* __restrict__ out,
                                            int K, int N) {
  __shared__ float t[32][33];
  int n0 = blockIdx.x * 32, k0 = blockIdx.y * 32;
  int tx = threadIdx.x, ty = threadIdx.y;  // 32 x 8
#pragma unroll
  for (int k = 0; k < 32; k += 8)
    t[ty + k][tx] = in[(size_t)(k0 + ty + k) * N + n0 + tx];
  __syncthreads();
#pragma unroll
  for (int k = 0; k < 32; k += 8)
    out[(size_t)(n0 + ty + k) * K + k0 + tx] = f2b(t[tx][ty + k]);
}

// ---------------------------------------------------------------------------
// LayerNorm over 768 channels (f32 in, bf16 out). One 256-thr block per row.
// ---------------------------------------------------------------------------
__device__ __forceinline__ float block_sum(float s, float* red) {
  __syncthreads();
#pragma unroll
  for (int off = 32; off > 0; off >>= 1) s += __shfl_down(s, off, 64);
  int wid = threadIdx.x >> 6, lane = threadIdx.x & 63;
  if (lane == 0) red[wid] = s;
  __syncthreads();
  return red[0] + red[1] + red[2] + red[3];
}

__global__ __launch_bounds__(256) void k_ln(const float* __restrict__ x,
                                            const float* __restrict__ wt,
                                            const float* __restrict__ bs,
                                            u16* __restrict__ y,
                                            int window_mode) {
  __shared__ float red[4];
  int row = blockIdx.x, tid = threadIdx.x;
  const float* xp = x + (size_t)row * CH;
  float v0 = xp[tid], v1 = xp[tid + 256], v2 = xp[tid + 512];
  float mu = block_sum(v0 + v1 + v2, red) * (1.0f / 768.0f);
  float d0 = v0 - mu, d1 = v1 - mu, d2 = v2 - mu;
  float var = block_sum(d0 * d0 + d1 * d1 + d2 * d2, red) * (1.0f / 768.0f);
  float rs = rsqrtf(var + 1e-6f);
  int orow = row;
  if (window_mode) {
    int b = row >> 12, hw = row & 4095;
    int h = hw >> 6, wc = hw & 63;
    orow = (b * 25 + (h / WSZ) * 5 + (wc / WSZ)) * NTOK + (h % WSZ) * WSZ + (wc % WSZ);
  }
  u16* yp = y + (size_t)orow * CH;
  yp[tid]       = f2b(d0 * rs * wt[tid]       + bs[tid]);
  yp[tid + 256] = f2b(d1 * rs * wt[tid + 256] + bs[tid + 256]);
  yp[tid + 512] = f2b(d2 * rs * wt[tid + 512] + bs[tid + 512]);
}

// ---------------------------------------------------------------------------
// Shared epilogue for both GEMM kernels.
// row/col absolute; thread holds 4 consecutive cols (quad*4+r) of one row.
// ---------------------------------------------------------------------------
__device__ __forceinline__ void gemm_epilogue_row(
    const f32x4* accrow, int row, int colbase, int N,
    const float* __restrict__ bias, void* __restrict__ Cv,
    u16* __restrict__ Vt, int act, int mode, int row0, int M) {
  if (row >= M) return;
  size_t gbase = 0;
  bool valid = true;
  int wloc = 0, tok = 0;
  if (mode == 2) {  // window slot -> image token (skip pad)
    int rowa = row + row0;
    int widx = rowa / NTOK, tt = rowa % NTOK;
    int b = widx / 25, wq = widx % 25;
    int h = (wq / 5) * WSZ + tt / WSZ;
    int w = (wq % 5) * WSZ + tt % WSZ;
    valid = (h < GRIDSZ) && (w < GRIDSZ);
    gbase = valid ? ((size_t)((b * GRIDSZ + h) * GRIDSZ + w)) * CH : 0;
  }
  if (mode == 3) { wloc = row / NTOK; tok = row - wloc * NTOK; }
#pragma unroll
  for (int ni = 0; ni < 4; ni++) {
    int colb = colbase + ni * 16;
    float4 b4 = *(const float4*)&bias[colb];
    float v[4] = {accrow[ni][0] + b4.x, accrow[ni][1] + b4.y,
                  accrow[ni][2] + b4.z, accrow[ni][3] + b4.w};
    if (act == 1) {
#pragma unroll
      for (int r2 = 0; r2 < 4; r2++) v[r2] = fast_gelu(v[r2]);
    }
    if (mode == 0) {
      ushort4 st = make_ushort4(f2b(v[0]), f2b(v[1]), f2b(v[2]), f2b(v[3]));
      *(ushort4*)((u16*)Cv + (size_t)row * N + colb) = st;
    } else if (mode == 1) {
      float4* p = (float4*)((float*)Cv + (size_t)row * N + colb);
      float4 o = *p;
      o.x += v[0]; o.y += v[1]; o.z += v[2]; o.w += v[3];
      *p = o;
    } else if (mode == 2) {
      if (valid) {
        float4* p = (float4*)((float*)Cv + gbase + colb);
        float4 o = *p;
        o.x += v[0]; o.y += v[1]; o.z += v[2]; o.w += v[3];
        *p = o;
      }
    } else {  // mode 3
      if (colb < 1536) {
        ushort4 st = make_ushort4(f2b(v[0]), f2b(v[1]), f2b(v[2]), f2b(v[3]));
        *(ushort4*)((u16*)Cv + (size_t)row * N + colb) = st;
      } else {
        int vv = colb - 1536, hd = vv >> 6, d = vv & 63;
        u16* vp = Vt + ((size_t)(wloc * NHEAD + hd) * 64 + d) * VSTR + tok;
#pragma unroll
        for (int r2 = 0; r2 < 4; r2++) vp[(size_t)r2 * VSTR] = f2b(v[r2]);
      }
    }
  }
}

// ---------------------------------------------------------------------------
// 8-wave scheduled bf16 MFMA GEMM: 256x256 tile, 512 thr (8 waves, 2Mx4N),
// wave tile 128x64 (acc[8][4]).  Ring-of-3 BK=32 slots (LDS 96KB, 1 blk/CU).
// Group T (tile kt): vmcnt(4) [per-wave: proves own 4 half-stages of tile T
// landed; after the barrier ALL waves' portions are landed] -> s_barrier ->
// ds_reads(slot T%3) interleaved with 4 half-stages of tile T+2 into the
// slot freed BY THIS BARRIER -> two setprio-wrapped 16-MFMA clusters.
// vmcnt ordering is per-wave FIFO: at B(T), newest 4 outstanding = tile T+1's
// halves; vmcnt(4) forces tile T's complete.  Last group: vmcnt(0).
// Granule XOR swizzle identical to the verified 0-conflict mapping:
// read granule quad^((l15>>1)&3); global source granule (c&3)^((c>>3)&3),
// LDS dest linear (gl_lds16-compatible).
// T1 XCD bijective chunking + GROUP_M ordering (L2-resident panels).
// Requires N%256==0, (K/32)%3==0 (K=768, K=3072 ok); M guarded.
// ---------------------------------------------------------------------------
__global__ __launch_bounds__(512, 1) void k_gemm8(const u16* __restrict__ A,
                                                  const u16* __restrict__ BT,
                                                  const float* __restrict__ bias,
                                                  void* __restrict__ Cv,
                                                  u16* __restrict__ Vt,
                                                  int M, int N, int K,
                                                  int act, int mode, int row0) {
  __shared__ u16 As[3][256 * 32];
  __shared__ u16 Bs[3][256 * 32];
  int tid  = threadIdx.x;
  int lane = tid & 63, wave = tid >> 6;      // 0..7

  // XCD bijective chunking + GROUP_M
  int gx = gridDim.x, gy = gridDim.y;
  int nwg = gx * gy;
  int orig = blockIdx.y * gx + blockIdx.x;
  int q = nwg >> 3, r = nwg & 7;
  int xcd = orig & 7, idx = orig >> 3;
  int wgid = (xcd < r ? xcd * (q + 1) : r * (q + 1) + (xcd - r) * q) + idx;
  int GM = 3145728 / (256 * K * 2);
  if (GM < 2) GM = 2;
  if (GM > gy) GM = gy;
  int gsz = GM * gx;
  int grp = wgid / gsz;
  int first = grp * GM;
  int gm = gy - first; if (gm > GM) gm = GM;
  int loc = wgid - grp * gsz;
  int bm = first + loc % gm;
  int bn = loc / gm;

  int wr = wave >> 2, wc = wave & 3;
  int l15 = lane & 15, quad = lane >> 4;
  int swz = (quad ^ ((l15 >> 1) & 3)) * 8;

  f32x4 acc[8][4];
#pragma unroll
  for (int i = 0; i < 8; i++)
#pragma unroll
    for (int j = 0; j < 4; j++) acc[i][j] = (f32x4){0.f, 0.f, 0.f, 0.f};

  const u16* Atile = A + (size_t)bm * 256 * K;
  const u16* Btile = BT + (size_t)bn * 256 * K;

  // staging invariants: chunk c = tid covers row c>>2 (of 128 in a half),
  // source granule (c&3)^((c>>3)&3); LDS dest linear at elem c*8.
  int rowc = tid >> 2;
  int gsv  = ((tid & 3) ^ ((tid >> 3) & 3)) * 8;
  const u16* pa = Atile + (size_t)rowc * K + gsv;
  const u16* pb = Btile + (size_t)rowc * K + gsv;
  int dstb = wave * 512;                     // + h*4096 (elems)

  int abase = (wr * 128 + l15) * 32 + swz;   // + mi*512
  int bbase = (wc * 64 + l15) * 32 + swz;    // + ni*512

  const int NT = K >> 5;                     // BK=32 tiles; NT%3==0, NT>=6

#define STG_A(S2, T2, h) \
  gl_lds16(pa + (size_t)(h) * 128 * K + (size_t)(T2) * 32, &As[(S2)][(h) * 4096 + dstb])
#define STG_B(S2, T2, h) \
  gl_lds16(pb + (size_t)(h) * 128 * K + (size_t)(T2) * 32, &Bs[(S2)][(h) * 4096 + dstb])

#define GROUP(S, T)                                                          \
  do {                                                                       \
    if ((T) + 1 < NT) asm volatile("s_waitcnt vmcnt(4)" ::: "memory");       \
    else              asm volatile("s_waitcnt vmcnt(0)" ::: "memory");       \
    __builtin_amdgcn_s_barrier();                                            \
    int T2_ = (T) + 2;                                                       \
    bool st_ = T2_ < NT;                                                     \
    bf16x8 bf_[4], af_[8];                                                   \
    _Pragma("unroll")                                                        \
    for (int ni = 0; ni < 4; ni++)                                           \
      bf_[ni] = *(const bf16x8*)&Bs[(S)][bbase + ni * 512];                  \
    _Pragma("unroll")                                                        \
    for (int mi = 0; mi < 4; mi++)                                           \
      af_[mi] = *(const bf16x8*)&As[(S)][abase + mi * 512];                  \
    if (st_) { STG_A(((S) + 2) % 3, T2_, 0); STG_A(((S) + 2) % 3, T2_, 1); } \
    _Pragma("unroll")                                                        \
    for (int mi = 4; mi < 8; mi++)                                           \
      af_[mi] = *(const bf16x8*)&As[(S)][abase + mi * 512];                  \
    __builtin_amdgcn_s_setprio(1);                                           \
    _Pragma("unroll")                                                        \
    for (int mi = 0; mi < 4; mi++)                                           \
      _Pragma("unroll")                                                      \
      for (int ni = 0; ni < 4; ni++)                                         \
        acc[mi][ni] = __builtin_amdgcn_mfma_f32_16x16x32_bf16(               \
            bf_[ni], af_[mi], acc[mi][ni], 0, 0, 0);                         \
    __builtin_amdgcn_s_setprio(0);                                           \
    if (st_) { STG_B(((S) + 2) % 3, T2_, 0); STG_B(((S) + 2) % 3, T2_, 1); } \
    __builtin_amdgcn_s_setprio(1);                                           \
    _Pragma("unroll")                                                        \
    for (int mi = 4; mi < 8; mi++)                                           \
      _Pragma("unroll")                                                      \
      for (int ni = 0; ni < 4; ni++)                                         \
        acc[mi][ni] = __builtin_amdgcn_mfma_f32_16x16x32_bf16(               \
            bf_[ni], af_[mi], acc[mi][ni], 0, 0, 0);                         \
    __builtin_amdgcn_s_setprio(0);                                           \
  } while (0)

  // prologue: tile 0 -> slot 0, tile 1 -> slot 1 (FIFO: tile0's 4 first)
  STG_A(0, 0, 0); STG_A(0, 0, 1); STG_B(0, 0, 0); STG_B(0, 0, 1);
  STG_A(1, 1, 0); STG_A(1, 1, 1); STG_B(1, 1, 0); STG_B(1, 1, 1);

  for (int kt = 0; kt < NT; kt += 3) {
    GROUP(0, kt);
    GROUP(1, kt + 1);
    GROUP(2, kt + 2);
  }

#undef GROUP
#undef STG_A
#undef STG_B

  // epilogue: row = bm*256 + wr*128 + mi*16 + l15 ; col = bn*256 + wc*64 + ni*16 + quad*4
#pragma unroll
  for (int mi = 0; mi < 8; mi++) {
    int row = bm * 256 + wr * 128 + mi * 16 + l15;
    int colbase = bn * 256 + wc * 64 + quad * 4;
    gemm_epilogue_row(acc[mi], row, colbase, N, bias, Cv, Vt, act, mode, row0, M);
  }
}

// ---------------------------------------------------------------------------
// 4-wave bf16 MFMA GEMM (R7-verified): 128x128 tile, ring-of-3 BK=32,
// counted vmcnt(4), K-loop unrolled by 3, granule swizzle, T1+GROUP_M.
// Used for proj/fc2 (N=768).  Requires (K/32)%3==0, K>=192, N%128==0.
// ---------------------------------------------------------------------------
__global__ __launch_bounds__(256, 3) void k_gemm_mfma(const u16* __restrict__ A,
                                                      const u16* __restrict__ BT,
                                                      const float* __restrict__ bias,
                                                      void* __restrict__ Cv,
                                                      u16* __restrict__ Vt,
                                                      int M, int N, int K,
                                                      int act, int mode, int row0) {
  __shared__ u16 As[3][128 * 32];
  __shared__ u16 Bs[3][128 * 32];
  int tid  = threadIdx.x;
  int lane = tid & 63, wave = tid >> 6;

  int gx   = gridDim.x, gy = gridDim.y;
  int nwg  = gx * gy;
  int orig = blockIdx.y * gx + blockIdx.x;
  int q = nwg >> 3, r = nwg & 7;
  int xcd = orig & 7, idx = orig >> 3;
  int wgid = (xcd < r ? xcd * (q + 1) : r * (q + 1) + (xcd - r) * q) + idx;

  int GM = 3145728 / (128 * K * 2);
  if (GM < 2) GM = 2;
  if (GM > gy) GM = gy;
  int gsz   = GM * gx;
  int grp   = wgid / gsz;
  int first = grp * GM;
  int gm    = gy - first; if (gm > GM) gm = GM;
  int loc   = wgid - grp * gsz;
  int bm    = first + loc % gm;
  int bn    = loc / gm;

  int wm = (wave & 1) * 64, wn = (wave >> 1) * 64;
  int l15 = lane & 15, quad = lane >> 4;
  int xq = (quad ^ ((l15 >> 1) & 3)) * 8;

  f32x4 acc[4][4];
#pragma unroll
  for (int i = 0; i < 4; i++)
#pragma unroll
    for (int j = 0; j < 4; j++) acc[i][j] = (f32x4){0.f, 0.f, 0.f, 0.f};

  const u16* Atile = A + (size_t)bm * 128 * K;
  const u16* Btile = BT + (size_t)bn * 128 * K;

  const u16* ga[2];
  const u16* gb[2];
#pragma unroll
  for (int i = 0; i < 2; ++i) {
    int c_ = i * 256 + wave * 64 + lane;
    int row_ = c_ >> 2, gs_ = (c_ & 3) ^ ((c_ >> 3) & 3);
    ga[i] = Atile + (size_t)row_ * K + gs_ * 8;
    gb[i] = Btile + (size_t)row_ * K + gs_ * 8;
  }

  const int nk = K >> 5;

#define STAGE(slot)                                                          \
  do {                                                                       \
    _Pragma("unroll")                                                        \
    for (int i = 0; i < 2; ++i) {                                            \
      gl_lds16(ga[i], &As[(slot)][(i * 256 + wave * 64) * 8]);               \
      ga[i] += 32;                                                           \
      gl_lds16(gb[i], &Bs[(slot)][(i * 256 + wave * 64) * 8]);               \
      gb[i] += 32;                                                           \
    }                                                                        \
  } while (0)

#define COMPUTE(slot)                                                        \
  do {                                                                       \
    bf16x8 af[4], bfv[4];                                                    \
    _Pragma("unroll")                                                        \
    for (int mi = 0; mi < 4; mi++)                                           \
      af[mi] = *(const bf16x8*)&As[(slot)][(wm + mi * 16 + l15) * 32 + xq];  \
    _Pragma("unroll")                                                        \
    for (int ni = 0; ni < 4; ni++)                                           \
      bfv[ni] = *(const bf16x8*)&Bs[(slot)][(wn + ni * 16 + l15) * 32 + xq]; \
    _Pragma("unroll")                                                        \
    for (int mi = 0; mi < 4; mi++)                                           \
      _Pragma("unroll")                                                      \
      for (int ni = 0; ni < 4; ni++)                                         \
        acc[mi][ni] = __builtin_amdgcn_mfma_f32_16x16x32_bf16(               \
            bfv[ni], af[mi], acc[mi][ni], 0, 0, 0);                          \
  } while (0)

#define WAITL                                                                \
  do {                                                                       \
    asm volatile("s_waitcnt vmcnt(4)" ::: "memory");                         \
    __builtin_amdgcn_s_barrier();                                            \
  } while (0)

  STAGE(0);
  STAGE(1);

  int t = 0;
  for (int g = 0; g < nk - 3; g += 3) {
    WAITL; STAGE(2); COMPUTE(0);
    WAITL; STAGE(0); COMPUTE(1);
    WAITL; STAGE(1); COMPUTE(2);
    t += 3;
  }
  WAITL; STAGE(2); COMPUTE(0);
  WAITL;           COMPUTE(1);
  asm volatile("s_waitcnt vmcnt(0)" ::: "memory");
  __builtin_amdgcn_s_barrier();
  COMPUTE(2);

#undef STAGE
#undef COMPUTE
#undef WAITL

#pragma unroll
  for (int mi = 0; mi < 4; mi++) {
    int row = bm * 128 + wm + mi * 16 + l15;
    int colbase = bn * 128 + wn + quad * 4;
    gemm_epilogue_row(acc[mi], row, colbase, N, bias, Cv, Vt, act, mode, row0, M);
  }
}

// ---------------------------------------------------------------------------
// Rel-pos bias tables from UNSCALED q: rhg/rwg[(wloc*12+head)*196+tok][16]
// ---------------------------------------------------------------------------
__global__ __launch_bounds__(256) void k_relbias(const u16* __restrict__ qkv,
                                                 const float* __restrict__ rel_h,
                                                 const float* __restrict__ rel_w,
                                                 u16* __restrict__ rhg,
                                                 u16* __restrict__ rwg,
                                                 int nrows) {
  int idx = blockIdx.x * 256 + threadIdx.x;
  if (idx >= nrows * NHEAD) return;
  int head = idx % NHEAD, row = idx / NHEAD;
  int wloc = row / NTOK, tok = row - wloc * NTOK;
  const u16* qp = qkv + (size_t)row * (3 * CH) + head * 64;
  float q[64];
#pragma unroll
  for (int d = 0; d < 64; d += 4) {
    ushort4 u4 = *(const ushort4*)(qp + d);
    q[d] = b2f(u4.x); q[d + 1] = b2f(u4.y); q[d + 2] = b2f(u4.z); q[d + 3] = b2f(u4.w);
  }
  int hq = tok / WSZ, wq = tok % WSZ;
  size_t obase = ((size_t)(wloc * NHEAD + head) * NTOK + tok) * 16;
  for (int kk = 0; kk < WSZ; kk++) {
    const float* rh = rel_h + (size_t)(hq - kk + WSZ - 1) * 64;
    const float* rw = rel_w + (size_t)(wq - kk + WSZ - 1) * 64;
    float sh = 0.0f, sw = 0.0f;
#pragma unroll
    for (int d = 0; d < 64; d++) { sh += q[d] * rh[d]; sw += q[d] * rw[d]; }
    rhg[obase + kk] = f2b(sh);
    rwg[obase + kk] = f2b(sw);
  }
}

// ---------------------------------------------------------------------------
// MFMA windowed attention. One block per (head, local window), 4 waves.
// ---------------------------------------------------------------------------
__global__ __launch_bounds__(256) void k_attn_mfma(const u16* __restrict__ qkv,
                                                   const u16* __restrict__ Vt,
                                                   const u16* __restrict__ rhg,
                                                   const u16* __restrict__ rwg,
                                                   u16* __restrict__ out,
                                                   int win0) {
  __shared__ u16 Ks[NTOK * KSTR];        // 28224 B
  __shared__ u16 Vs[64 * VSTR];          // 27648 B
  __shared__ u16 Ps[4][16 * PSTR];       // 5120 B
  int head = blockIdx.x, wloc = blockIdx.y;
  int tid = threadIdx.x, lane = tid & 63, wave = tid >> 6;
  int l15 = lane & 15, quad = lane >> 4;
  const u16* qbase = qkv + (size_t)wloc * NTOK * (3 * CH) + head * 64;

  for (int c = tid; c < NTOK * 8; c += 256) {
    int tok = c >> 3, part = c & 7;
    uint4 v = *(const uint4*)(qbase + (size_t)tok * (3 * CH) + CH + part * 8);
    *(uint4*)&Ks[tok * KSTR + part * 8] = v;
  }
  const u16* vb = Vt + (size_t)(wloc * NHEAD + head) * 64 * VSTR;
#pragma unroll
  for (int it = 0; it < 7; ++it) {
    int c = it * 256 + tid;
    if (c < 64 * VSTR / 8) gl_lds16(vb + (size_t)c * 8, Vs + ((size_t)it * 256 + wave * 64) * 8);
  }
  __syncthreads();

  const u16* rhp = rhg + ((size_t)(wloc * NHEAD + head) * NTOK) * 16;
  const u16* rwp = rwg + ((size_t)(wloc * NHEAD + head) * NTOK) * 16;
  int winabs = win0 + wloc;

  for (int t16 = wave; t16 < 13; t16 += 4) {
    int qtok = t16 * 16 + l15; if (qtok > NTOK - 1) qtok = NTOK - 1;
    bf16x8 aq0 = *(const bf16x8*)(qbase + (size_t)qtok * (3 * CH) + quad * 8);
    bf16x8 aq1 = *(const bf16x8*)(qbase + (size_t)qtok * (3 * CH) + 32 + quad * 8);

    f32x4 s[13];
#pragma unroll
    for (int ct = 0; ct < 13; ct++) s[ct] = (f32x4){0.f, 0.f, 0.f, 0.f};
#pragma unroll
    for (int ct = 0; ct < 13; ct++) {
      int ktok = ct * 16 + l15; if (ktok > NTOK - 1) ktok = NTOK - 1;
      bf16x8 bk0 = *(const bf16x8*)&Ks[ktok * KSTR + quad * 8];
      bf16x8 bk1 = *(const bf16x8*)&Ks[ktok * KSTR + 32 + quad * 8];
      s[ct] = __builtin_amdgcn_mfma_f32_16x16x32_bf16(aq0, bk0, s[ct], 0, 0, 0);
      s[ct] = __builtin_amdgcn_mfma_f32_16x16x32_bf16(aq1, bk1, s[ct], 0, 0, 0);
    }

    f32x4 o[4];
#pragma unroll
    for (int ni = 0; ni < 4; ni++) o[ni] = (f32x4){0.f, 0.f, 0.f, 0.f};
    float lsum[4] = {0.f, 0.f, 0.f, 0.f};
    int row0t = t16 * 16 + quad * 4;

#pragma unroll
    for (int cc = 0; cc < 7; ++cc) {
#pragma unroll
      for (int half = 0; half < 2; ++half) {
        int ct = cc * 2 + half;
        if (ct < 13) {
          int col = ct * 16 + l15;
          int jh = col / WSZ, jw = col - jh * WSZ;
          bool colok = col < NTOK;
#pragma unroll
          for (int r = 0; r < 4; r++) {
            int rowt = row0t + r; int rowc = rowt > NTOK - 1 ? NTOK - 1 : rowt;
            float bias = b2f(rhp[rowc * 16 + jh]) + b2f(rwp[rowc * 16 + jw]);
            float sv = s[ct][r] * QKSCALE + bias;
            float p = colok ? __expf(sv) : 0.f;
            lsum[r] += p;
            Ps[wave][(quad * 4 + r) * PSTR + half * 16 + l15] = f2b(p);
          }
        } else {
#pragma unroll
          for (int r = 0; r < 4; r++)
            Ps[wave][(quad * 4 + r) * PSTR + half * 16 + l15] = 0;
        }
      }
      bf16x8 pa = *(const bf16x8*)&Ps[wave][l15 * PSTR + quad * 8];
#pragma unroll
      for (int ni = 0; ni < 4; ni++) {
        bf16x8 bv = *(const bf16x8*)&Vs[(ni * 16 + l15) * VSTR + cc * 32 + quad * 8];
        o[ni] = __builtin_amdgcn_mfma_f32_16x16x32_bf16(pa, bv, o[ni], 0, 0, 0);
      }
    }

#pragma unroll
    for (int r = 0; r < 4; r++) {
#pragma unroll
      for (int m = 1; m < 16; m <<= 1) lsum[r] += __shfl_xor(lsum[r], m, 64);
    }

#pragma unroll
    for (int r = 0; r < 4; r++) {
      int rowt = row0t + r;
      if (rowt < NTOK) {
        float inv = 1.0f / lsum[r];
        u16* op = out + ((size_t)winabs * NTOK + rowt) * CH + head * 64;
#pragma unroll
        for (int ni = 0; ni < 4; ni++) op[ni * 16 + l15] = f2b(o[ni][r] * inv);
      }
    }
  }
}

// ---------------------------------------------------------------------------
extern "C" void kernel_launch(void* const* d_in, const int* in_sizes, int n_in,
                              void* d_out, int out_size, void* d_ws, size_t ws_size,
                              hipStream_t stream) {
  const float* hidden = (const float*)d_in[0];
  const float* ln1_w  = (const float*)d_in[1];
  const float* ln1_b  = (const float*)d_in[2];
  const float* qkv_w  = (const float*)d_in[3];
  const float* qkv_b  = (const float*)d_in[4];
  const float* proj_w = (const float*)d_in[5];
  const float* proj_b = (const float*)d_in[6];
  const float* rel_h  = (const float*)d_in[7];
  const float* rel_w  = (const float*)d_in[8];
  const float* ln2_w  = (const float*)d_in[9];
  const float* ln2_b  = (const float*)d_in[10];
  const float* fc1_w  = (const float*)d_in[11];
  const float* fc1_b  = (const float*)d_in[12];
  const float* fc2_w  = (const float*)d_in[13];
  const float* fc2_b  = (const float*)d_in[14];
  float* out = (float*)d_out;

  char* ws = (char*)d_ws;
  float* x_nhwc = (float*)ws;
  u16*   R1     = (u16*)(ws + 50331648);
  u16*   qkvT   = (u16*)(ws + 80437248);
  u16*   projT  = qkvT + (size_t)2304 * 768;
  u16*   fc1T   = projT + (size_t)768 * 768;
  u16*   fc2T   = fc1T + (size_t)3072 * 768;
  u16*   R2     = fc2T + (size_t)768 * 3072;
  size_t used   = (size_t)80437248 + 14155776;
  size_t r2e    = ws_size > used ? (ws_size - used) >> 1 : 0;  // bf16 elems

  const size_t PW_QKV = (size_t)NTOK * 3 * CH;            // 451584
  const size_t PW_VT  = (size_t)NHEAD * 64 * VSTR;        // 165888
  const size_t PW_RB  = (size_t)NHEAD * NTOK * 16;        // 37632 (x2 tables)
  const size_t perwin = PW_QKV + PW_VT + 2 * PW_RB;       // 692736 elems
  size_t wc_s = r2e / perwin;
  int Wc = wc_s >= NWINS ? NWINS : (int)wc_s;
  if (Wc < 1) Wc = 1;
  size_t rc_s = (r2e / MLPC / 256) * 256;
  int Rc = rc_s >= MREAL ? MREAL : (int)rc_s;
  if (Rc < 256) Rc = 256;

  u16* Vt  = R2 + (size_t)Wc * PW_QKV;
  u16* rhg = Vt + (size_t)Wc * PW_VT;
  u16* rwg = rhg + (size_t)Wc * PW_RB;

  // 0) weight convert + transpose
  k_wt<<<dim3(72, 24), dim3(32, 8), 0, stream>>>(qkv_w, qkvT, CH, 3 * CH);
  k_wt<<<dim3(24, 24), dim3(32, 8), 0, stream>>>(proj_w, projT, CH, CH);
  k_wt<<<dim3(96, 24), dim3(32, 8), 0, stream>>>(fc1_w, fc1T, CH, MLPC);
  k_wt<<<dim3(24, 96), dim3(32, 8), 0, stream>>>(fc2_w, fc2T, MLPC, CH);

  hipMemsetAsync(R1, 0, (size_t)MWIN * CH * sizeof(u16), stream);

  // 1) NCHW -> NHWC
  k_nchw2nhwc<<<dim3(128, 24, NIMG), dim3(32, 8), 0, stream>>>(hidden, x_nhwc);
  // 2) LN1 -> window-partitioned xln
  k_ln<<<MREAL, 256, 0, stream>>>(x_nhwc, ln1_w, ln1_b, R1, 1);
  // 3+4) per window chunk: qkv GEMM (8-wave) -> rel bias -> attn
  for (int w0 = 0; w0 < NWINS; w0 += Wc) {
    int wc = NWINS - w0 < Wc ? NWINS - w0 : Wc;
    int Mc = wc * NTOK;
    k_gemm8<<<dim3(9, (Mc + 255) / 256), 512, 0, stream>>>(
        R1 + (size_t)w0 * NTOK * CH, qkvT, qkv_b, R2, Vt,
        Mc, 3 * CH, CH, 0, 3, 0);
    k_relbias<<<(Mc * NHEAD + 255) / 256, 256, 0, stream>>>(
        R2, rel_h, rel_w, rhg, rwg, Mc);
    k_attn_mfma<<<dim3(NHEAD, wc), 256, 0, stream>>>(
        R2, Vt, rhg, rwg, R1, w0);
  }
  // 5) proj + window-unpartition residual add (4-wave control kernel)
  k_gemm_mfma<<<dim3(6, (MWIN + 127) / 128), 256, 0, stream>>>(
      R1, projT, proj_b, x_nhwc, nullptr, MWIN, CH, CH, 0, 2, 0);
  // 6) LN2
  k_ln<<<MREAL, 256, 0, stream>>>(x_nhwc, ln2_w, ln2_b, R1, 0);
  // 7+8) fc1 (8-wave) -> GELU -> fc2 (4-wave control)
  for (int r0 = 0; r0 < MREAL; r0 += Rc) {
    int rc = MREAL - r0 < Rc ? MREAL - r0 : Rc;
    k_gemm8<<<dim3(12, (rc + 255) / 256), 512, 0, stream>>>(
        R1 + (size_t)r0 * CH, fc1T, fc1_b, R2, nullptr, rc, MLPC, CH, 1, 0, 0);
    k_gemm_mfma<<<dim3(6, (rc + 127) / 128), 256, 0, stream>>>(
        R2, fc2T, fc2_b, x_nhwc + (size_t)r0 * CH, nullptr, rc, CH, MLPC, 0, 1, 0);
  }
  // 9) NHWC -> NCHW output
  k_nhwc2nchw<<<dim3(128, 24, NIMG), dim3(32, 8), 0, stream>>>(x_nhwc, out);
}

// Round 9
// 745.604 us; speedup vs baseline: 1.1392x; 1.1392x over previous
//
#include <hip/hip_runtime.h>
#include <cstdint>
#include <cstddef>

// Problem constants (ViTDet block, B=4, 64x64, DIM=768, 14x14 windows)
#define NIMG   4
#define GRIDSZ 64          // H = W = 64
#define CH     768
#define NHEAD  12
#define WSZ    14
#define NWINS  100         // 4 images * 5*5 windows
#define NTOK   196         // 14*14
#define MWIN   19600       // NWINS*NTOK
#define MREAL  16384       // 4*64*64
#define MLPC   3072
#define QKSCALE 0.125f

#define KSTR 72            // Ks LDS row stride (u16)
#define VSTR 216           // Vt row stride (u16)
#define PSTR 40            // P slice row stride (u16)

typedef unsigned short u16;
typedef __attribute__((ext_vector_type(8))) short bf16x8;
typedef __attribute__((ext_vector_type(4))) float f32x4;

__device__ __forceinline__ float b2f(u16 u) {
  uint32_t x = (uint32_t)u << 16; float f; __builtin_memcpy(&f, &x, 4); return f;
}
__device__ __forceinline__ u16 f2b(float f) {
  uint32_t x; __builtin_memcpy(&x, &f, 4);
  x += 0x7fffu + ((x >> 16) & 1u);           // round-to-nearest-even
  return (u16)(x >> 16);
}

// Fast exact-GELU: erf via Abramowitz-Stegun 7.1.26 (|err| <= 1.5e-7).
__device__ __forceinline__ float fast_gelu(float x) {
  float z  = x * 0.70710678118654752440f;
  float az = fabsf(z);
  float t  = 1.0f / (1.0f + 0.3275911f * az);
  float poly = ((((1.061405429f * t - 1.453152027f) * t + 1.421413741f) * t
                 - 0.284496736f) * t + 0.254829592f) * t;
  float e  = __expf(-az * az);
  float erfv = copysignf(1.0f - poly * e, z);
  return 0.5f * x * (1.0f + erfv);
}

// async global->LDS, 16B per lane; lds base must be wave-uniform
__device__ __forceinline__ void gl_lds16(const u16* g, u16* l) {
  __builtin_amdgcn_global_load_lds(
      (const __attribute__((address_space(1))) unsigned int*)g,
      (__attribute__((address_space(3))) unsigned int*)l, 16, 0, 0);
}

// ---------------------------------------------------------------------------
// Transpose NCHW -> NHWC  (f32 -> f32), 32x32 LDS tiles
// ---------------------------------------------------------------------------
__global__ __launch_bounds__(256) void k_nchw2nhwc(const float* __restrict__ in,
                                                   float* __restrict__ out) {
  __shared__ float tile[32][33];
  int b  = blockIdx.z;
  int g0 = blockIdx.x * 32;
  int c0 = blockIdx.y * 32;
  int tx = threadIdx.x, ty = threadIdx.y;  // 32 x 8
  const float* ip = in + (size_t)b * CH * 4096;
  float* op = out + (size_t)b * 4096 * CH;
#pragma unroll
  for (int k = 0; k < 32; k += 8)
    tile[ty + k][tx] = ip[(size_t)(c0 + ty + k) * 4096 + g0 + tx];
  __syncthreads();
#pragma unroll
  for (int k = 0; k < 32; k += 8)
    op[(size_t)(g0 + ty + k) * CH + c0 + tx] = tile[tx][ty + k];
}

__global__ __launch_bounds__(256) void k_nhwc2nchw(const float* __restrict__ in,
                                                   float* __restrict__ out) {
  __shared__ float tile[32][33];
  int b  = blockIdx.z;
  int g0 = blockIdx.x * 32;
  int c0 = blockIdx.y * 32;
  int tx = threadIdx.x, ty = threadIdx.y;
  const float* ip = in + (size_t)b * 4096 * CH;
  float* op = out + (size_t)b * CH * 4096;
#pragma unroll
  for (int k = 0; k < 32; k += 8)
    tile[ty + k][tx] = ip[(size_t)(g0 + ty + k) * CH + c0 + tx];
  __syncthreads();
#pragma unroll
  for (int k = 0; k < 32; k += 8)
    op[(size_t)(c0 + ty + k) * 4096 + g0 + tx] = tile[tx][ty + k];
}

// ---------------------------------------------------------------------------
// Weight convert+transpose: in f32 [K][N] -> out bf16 [N][K]
// ---------------------------------------------------------------------------
__global__ __launch_bounds__(256) void k_wt(const float* __restrict__ in,
                                            u16* __restrict__ out,
                                            int K, int N) {
  __shared__ float t[32][33];
  int n0 = blockIdx.x * 32, k0 = blockIdx.y * 32;
  int tx = threadIdx.x, ty = threadIdx.y;  // 32 x 8
#pragma unroll
  for (int k = 0; k < 32; k += 8)
    t[ty + k][tx] = in[(size_t)(k0 + ty + k) * N + n0 + tx];
  __syncthreads();
#pragma unroll
  for (int k = 0; k < 32; k += 8)
    out[(size_t)(n0 + ty + k) * K + k0 + tx] = f2b(t[tx][ty + k]);
}

// ---------------------------------------------------------------------------
// LayerNorm over 768 channels (f32 in, bf16 out). WAVE-per-row (no barriers,
// no LDS): 12 f32/lane as 6x float2, two __shfl_xor reductions. 4 rows/block.
// ---------------------------------------------------------------------------
__global__ __launch_bounds__(256) void k_ln(const float* __restrict__ x,
                                            const float* __restrict__ wt,
                                            const float* __restrict__ bs,
                                            u16* __restrict__ y,
                                            int window_mode) {
  int wid = threadIdx.x >> 6, lane = threadIdx.x & 63;
  int row = blockIdx.x * 4 + wid;
  const float* xp = x + (size_t)row * CH;
  float v[12];
#pragma unroll
  for (int k = 0; k < 6; k++) {
    float2 f2 = *(const float2*)&xp[k * 128 + lane * 2];
    v[2 * k] = f2.x; v[2 * k + 1] = f2.y;
  }
  float s = 0.f;
#pragma unroll
  for (int k = 0; k < 12; k++) s += v[k];
#pragma unroll
  for (int off = 32; off > 0; off >>= 1) s += __shfl_xor(s, off, 64);
  float mu = s * (1.0f / 768.0f);
  float vs = 0.f;
#pragma unroll
  for (int k = 0; k < 12; k++) { float d = v[k] - mu; vs += d * d; }
#pragma unroll
  for (int off = 32; off > 0; off >>= 1) vs += __shfl_xor(vs, off, 64);
  float rs = rsqrtf(vs * (1.0f / 768.0f) + 1e-6f);
  int orow = row;
  if (window_mode) {
    int b = row >> 12, hw = row & 4095;
    int h = hw >> 6, wc = hw & 63;
    orow = (b * 25 + (h / WSZ) * 5 + (wc / WSZ)) * NTOK + (h % WSZ) * WSZ + (wc % WSZ);
  }
  u16* yp = y + (size_t)orow * CH;
#pragma unroll
  for (int k = 0; k < 6; k++) {
    int c = k * 128 + lane * 2;
    float2 w2 = *(const float2*)&wt[c];
    float2 b2 = *(const float2*)&bs[c];
    ushort2 st = make_ushort2(f2b((v[2 * k] - mu) * rs * w2.x + b2.x),
                              f2b((v[2 * k + 1] - mu) * rs * w2.y + b2.y));
    *(ushort2*)&yp[c] = st;
  }
}

// ---------------------------------------------------------------------------
// Shared epilogue for the GEMM kernel.
// row/col absolute; thread holds 4 consecutive cols (quad*4+r) of one row.
// ---------------------------------------------------------------------------
__device__ __forceinline__ void gemm_epilogue_row(
    const f32x4* accrow, int row, int colbase, int N,
    const float* __restrict__ bias, void* __restrict__ Cv,
    u16* __restrict__ Vt, int act, int mode, int row0, int M) {
  if (row >= M) return;
  size_t gbase = 0;
  bool valid = true;
  int wloc = 0, tok = 0;
  if (mode == 2) {  // window slot -> image token (skip pad)
    int rowa = row + row0;
    int widx = rowa / NTOK, tt = rowa % NTOK;
    int b = widx / 25, wq = widx % 25;
    int h = (wq / 5) * WSZ + tt / WSZ;
    int w = (wq % 5) * WSZ + tt % WSZ;
    valid = (h < GRIDSZ) && (w < GRIDSZ);
    gbase = valid ? ((size_t)((b * GRIDSZ + h) * GRIDSZ + w)) * CH : 0;
  }
  if (mode == 3) { wloc = row / NTOK; tok = row - wloc * NTOK; }
#pragma unroll
  for (int ni = 0; ni < 4; ni++) {
    int colb = colbase + ni * 16;
    float4 b4 = *(const float4*)&bias[colb];
    float v[4] = {accrow[ni][0] + b4.x, accrow[ni][1] + b4.y,
                  accrow[ni][2] + b4.z, accrow[ni][3] + b4.w};
    if (act == 1) {
#pragma unroll
      for (int r2 = 0; r2 < 4; r2++) v[r2] = fast_gelu(v[r2]);
    }
    if (mode == 0) {
      ushort4 st = make_ushort4(f2b(v[0]), f2b(v[1]), f2b(v[2]), f2b(v[3]));
      *(ushort4*)((u16*)Cv + (size_t)row * N + colb) = st;
    } else if (mode == 1) {
      float4* p = (float4*)((float*)Cv + (size_t)row * N + colb);
      float4 o = *p;
      o.x += v[0]; o.y += v[1]; o.z += v[2]; o.w += v[3];
      *p = o;
    } else if (mode == 2) {
      if (valid) {
        float4* p = (float4*)((float*)Cv + gbase + colb);
        float4 o = *p;
        o.x += v[0]; o.y += v[1]; o.z += v[2]; o.w += v[3];
        *p = o;
      }
    } else {  // mode 3
      if (colb < 1536) {
        ushort4 st = make_ushort4(f2b(v[0]), f2b(v[1]), f2b(v[2]), f2b(v[3]));
        *(ushort4*)((u16*)Cv + (size_t)row * N + colb) = st;
      } else {
        int vv = colb - 1536, hd = vv >> 6, d = vv & 63;
        u16* vp = Vt + ((size_t)(wloc * NHEAD + hd) * 64 + d) * VSTR + tok;
#pragma unroll
        for (int r2 = 0; r2 < 4; r2++) vp[(size_t)r2 * VSTR] = f2b(v[r2]);
      }
    }
  }
}

// ---------------------------------------------------------------------------
// 4-wave bf16 MFMA GEMM (R7-verified best): 128x128 tile, ring-of-3 BK=32,
// counted vmcnt(4), K-loop unrolled by 3 (compile-time slots), granule XOR
// swizzle (0 bank conflicts), T1 XCD bijective chunking + GROUP_M ordering.
// LDS 48 KB, 3 blocks/CU.  Requires (K/32)%3==0, K>=192, N%128==0.
// ---------------------------------------------------------------------------
__global__ __launch_bounds__(256, 3) void k_gemm_mfma(const u16* __restrict__ A,
                                                      const u16* __restrict__ BT,
                                                      const float* __restrict__ bias,
                                                      void* __restrict__ Cv,
                                                      u16* __restrict__ Vt,
                                                      int M, int N, int K,
                                                      int act, int mode, int row0) {
  __shared__ u16 As[3][128 * 32];
  __shared__ u16 Bs[3][128 * 32];
  int tid  = threadIdx.x;
  int lane = tid & 63, wave = tid >> 6;

  int gx   = gridDim.x, gy = gridDim.y;
  int nwg  = gx * gy;
  int orig = blockIdx.y * gx + blockIdx.x;
  int q = nwg >> 3, r = nwg & 7;
  int xcd = orig & 7, idx = orig >> 3;
  int wgid = (xcd < r ? xcd * (q + 1) : r * (q + 1) + (xcd - r) * q) + idx;

  int GM = 3145728 / (128 * K * 2);
  if (GM < 2) GM = 2;
  if (GM > gy) GM = gy;
  int gsz   = GM * gx;
  int grp   = wgid / gsz;
  int first = grp * GM;
  int gm    = gy - first; if (gm > GM) gm = GM;
  int loc   = wgid - grp * gsz;
  int bm    = first + loc % gm;
  int bn    = loc / gm;

  int wm = (wave & 1) * 64, wn = (wave >> 1) * 64;
  int l15 = lane & 15, quad = lane >> 4;
  int xq = (quad ^ ((l15 >> 1) & 3)) * 8;

  f32x4 acc[4][4];
#pragma unroll
  for (int i = 0; i < 4; i++)
#pragma unroll
    for (int j = 0; j < 4; j++) acc[i][j] = (f32x4){0.f, 0.f, 0.f, 0.f};

  const u16* Atile = A + (size_t)bm * 128 * K;
  const u16* Btile = BT + (size_t)bn * 128 * K;

  const u16* ga[2];
  const u16* gb[2];
#pragma unroll
  for (int i = 0; i < 2; ++i) {
    int c_ = i * 256 + wave * 64 + lane;
    int row_ = c_ >> 2, gs_ = (c_ & 3) ^ ((c_ >> 3) & 3);
    ga[i] = Atile + (size_t)row_ * K + gs_ * 8;
    gb[i] = Btile + (size_t)row_ * K + gs_ * 8;
  }

  const int nk = K >> 5;

#define STAGE(slot)                                                          \
  do {                                                                       \
    _Pragma("unroll")                                                        \
    for (int i = 0; i < 2; ++i) {                                            \
      gl_lds16(ga[i], &As[(slot)][(i * 256 + wave * 64) * 8]);               \
      ga[i] += 32;                                                           \
      gl_lds16(gb[i], &Bs[(slot)][(i * 256 + wave * 64) * 8]);               \
      gb[i] += 32;                                                           \
    }                                                                        \
  } while (0)

#define COMPUTE(slot)                                                        \
  do {                                                                       \
    bf16x8 af[4], bfv[4];                                                    \
    _Pragma("unroll")                                                        \
    for (int mi = 0; mi < 4; mi++)                                           \
      af[mi] = *(const bf16x8*)&As[(slot)][(wm + mi * 16 + l15) * 32 + xq];  \
    _Pragma("unroll")                                                        \
    for (int ni = 0; ni < 4; ni++)                                           \
      bfv[ni] = *(const bf16x8*)&Bs[(slot)][(wn + ni * 16 + l15) * 32 + xq]; \
    _Pragma("unroll")                                                        \
    for (int mi = 0; mi < 4; mi++)                                           \
      _Pragma("unroll")                                                      \
      for (int ni = 0; ni < 4; ni++)                                         \
        acc[mi][ni] = __builtin_amdgcn_mfma_f32_16x16x32_bf16(               \
            bfv[ni], af[mi], acc[mi][ni], 0, 0, 0);                          \
  } while (0)

#define WAITL                                                                \
  do {                                                                       \
    asm volatile("s_waitcnt vmcnt(4)" ::: "memory");                         \
    __builtin_amdgcn_s_barrier();                                            \
  } while (0)

  STAGE(0);
  STAGE(1);

  for (int g = 0; g < nk - 3; g += 3) {
    WAITL; STAGE(2); COMPUTE(0);
    WAITL; STAGE(0); COMPUTE(1);
    WAITL; STAGE(1); COMPUTE(2);
  }
  WAITL; STAGE(2); COMPUTE(0);
  WAITL;           COMPUTE(1);
  asm volatile("s_waitcnt vmcnt(0)" ::: "memory");
  __builtin_amdgcn_s_barrier();
  COMPUTE(2);

#undef STAGE
#undef COMPUTE
#undef WAITL

#pragma unroll
  for (int mi = 0; mi < 4; mi++) {
    int row = bm * 128 + wm + mi * 16 + l15;
    int colbase = bn * 128 + wn + quad * 4;
    gemm_epilogue_row(acc[mi], row, colbase, N, bias, Cv, Vt, act, mode, row0, M);
  }
}

// ---------------------------------------------------------------------------
// Rel-pos bias tables from UNSCALED q: rhg/rwg[(wloc*12+head)*196+tok][16]
// ---------------------------------------------------------------------------
__global__ __launch_bounds__(256) void k_relbias(const u16* __restrict__ qkv,
                                                 const float* __restrict__ rel_h,
                                                 const float* __restrict__ rel_w,
                                                 u16* __restrict__ rhg,
                                                 u16* __restrict__ rwg,
                                                 int nrows) {
  int idx = blockIdx.x * 256 + threadIdx.x;
  if (idx >= nrows * NHEAD) return;
  int head = idx % NHEAD, row = idx / NHEAD;
  int wloc = row / NTOK, tok = row - wloc * NTOK;
  const u16* qp = qkv + (size_t)row * (3 * CH) + head * 64;
  float q[64];
#pragma unroll
  for (int d = 0; d < 64; d += 4) {
    ushort4 u4 = *(const ushort4*)(qp + d);
    q[d] = b2f(u4.x); q[d + 1] = b2f(u4.y); q[d + 2] = b2f(u4.z); q[d + 3] = b2f(u4.w);
  }
  int hq = tok / WSZ, wq = tok % WSZ;
  size_t obase = ((size_t)(wloc * NHEAD + head) * NTOK + tok) * 16;
  for (int kk = 0; kk < WSZ; kk++) {
    const float* rh = rel_h + (size_t)(hq - kk + WSZ - 1) * 64;
    const float* rw = rel_w + (size_t)(wq - kk + WSZ - 1) * 64;
    float sh = 0.0f, sw = 0.0f;
#pragma unroll
    for (int d = 0; d < 64; d++) { sh += q[d] * rh[d]; sw += q[d] * rw[d]; }
    rhg[obase + kk] = f2b(sh);
    rwg[obase + kk] = f2b(sw);
  }
}

// ---------------------------------------------------------------------------
// MFMA windowed attention. One block per (head, local window), 4 waves.
// Ks: [196][KSTR] bf16; Vs: V^T [64][VSTR]; RhL/RwL: rel-bias tables staged
// in LDS (removes ~16 scalar GLOBAL u16 loads per lane per cc-iter from the
// softmax critical path between QK^T and PV).  Total LDS 73.5 KB, 2 blk/CU.
// ---------------------------------------------------------------------------
__global__ __launch_bounds__(256) void k_attn_mfma(const u16* __restrict__ qkv,
                                                   const u16* __restrict__ Vt,
                                                   const u16* __restrict__ rhg,
                                                   const u16* __restrict__ rwg,
                                                   u16* __restrict__ out,
                                                   int win0) {
  __shared__ u16 Ks[NTOK * KSTR];        // 28224 B
  __shared__ u16 Vs[64 * VSTR];          // 27648 B
  __shared__ u16 Ps[4][16 * PSTR];       // 5120 B
  __shared__ u16 RhL[NTOK * 16];         // 6272 B
  __shared__ u16 RwL[NTOK * 16];         // 6272 B   (total 73536 B)
  int head = blockIdx.x, wloc = blockIdx.y;
  int tid = threadIdx.x, lane = tid & 63, wave = tid >> 6;
  int l15 = lane & 15, quad = lane >> 4;
  const u16* qbase = qkv + (size_t)wloc * NTOK * (3 * CH) + head * 64;

  // stage K rows (196 x 64) -> Ks stride 72
  for (int c = tid; c < NTOK * 8; c += 256) {
    int tok = c >> 3, part = c & 7;
    uint4 v = *(const uint4*)(qbase + (size_t)tok * (3 * CH) + CH + part * 8);
    *(uint4*)&Ks[tok * KSTR + part * 8] = v;
  }
  // stage rel-bias tables (2 x 3136 u16 = 2 x 392 uint4)
  {
    const uint4* rhp4 = (const uint4*)(rhg + ((size_t)(wloc * NHEAD + head) * NTOK) * 16);
    const uint4* rwp4 = (const uint4*)(rwg + ((size_t)(wloc * NHEAD + head) * NTOK) * 16);
    for (int c = tid; c < NTOK * 2; c += 256) {
      ((uint4*)RhL)[c] = rhp4[c];
      ((uint4*)RwL)[c] = rwp4[c];
    }
  }
  // stage V^T via global_load_lds
  const u16* vb = Vt + (size_t)(wloc * NHEAD + head) * 64 * VSTR;
#pragma unroll
  for (int it = 0; it < 7; ++it) {
    int c = it * 256 + tid;
    if (c < 64 * VSTR / 8) gl_lds16(vb + (size_t)c * 8, Vs + ((size_t)it * 256 + wave * 64) * 8);
  }
  __syncthreads();

  int winabs = win0 + wloc;

  for (int t16 = wave; t16 < 13; t16 += 4) {
    int qtok = t16 * 16 + l15; if (qtok > NTOK - 1) qtok = NTOK - 1;
    bf16x8 aq0 = *(const bf16x8*)(qbase + (size_t)qtok * (3 * CH) + quad * 8);
    bf16x8 aq1 = *(const bf16x8*)(qbase + (size_t)qtok * (3 * CH) + 32 + quad * 8);

    f32x4 s[13];
#pragma unroll
    for (int ct = 0; ct < 13; ct++) s[ct] = (f32x4){0.f, 0.f, 0.f, 0.f};
#pragma unroll
    for (int ct = 0; ct < 13; ct++) {
      int ktok = ct * 16 + l15; if (ktok > NTOK - 1) ktok = NTOK - 1;
      bf16x8 bk0 = *(const bf16x8*)&Ks[ktok * KSTR + quad * 8];
      bf16x8 bk1 = *(const bf16x8*)&Ks[ktok * KSTR + 32 + quad * 8];
      s[ct] = __builtin_amdgcn_mfma_f32_16x16x32_bf16(aq0, bk0, s[ct], 0, 0, 0);
      s[ct] = __builtin_amdgcn_mfma_f32_16x16x32_bf16(aq1, bk1, s[ct], 0, 0, 0);
    }

    f32x4 o[4];
#pragma unroll
    for (int ni = 0; ni < 4; ni++) o[ni] = (f32x4){0.f, 0.f, 0.f, 0.f};
    float lsum[4] = {0.f, 0.f, 0.f, 0.f};
    int row0t = t16 * 16 + quad * 4;

#pragma unroll
    for (int cc = 0; cc < 7; ++cc) {
#pragma unroll
      for (int half = 0; half < 2; ++half) {
        int ct = cc * 2 + half;
        if (ct < 13) {
          int col = ct * 16 + l15;
          int jh = col / WSZ, jw = col - jh * WSZ;
          bool colok = col < NTOK;
#pragma unroll
          for (int r = 0; r < 4; r++) {
            int rowt = row0t + r; int rowc = rowt > NTOK - 1 ? NTOK - 1 : rowt;
            float bias = b2f(RhL[rowc * 16 + jh]) + b2f(RwL[rowc * 16 + jw]);
            float sv = s[ct][r] * QKSCALE + bias;
            float p = colok ? __expf(sv) : 0.f;
            lsum[r] += p;
            Ps[wave][(quad * 4 + r) * PSTR + half * 16 + l15] = f2b(p);
          }
        } else {
#pragma unroll
          for (int r = 0; r < 4; r++)
            Ps[wave][(quad * 4 + r) * PSTR + half * 16 + l15] = 0;
        }
      }
      bf16x8 pa = *(const bf16x8*)&Ps[wave][l15 * PSTR + quad * 8];
#pragma unroll
      for (int ni = 0; ni < 4; ni++) {
        bf16x8 bv = *(const bf16x8*)&Vs[(ni * 16 + l15) * VSTR + cc * 32 + quad * 8];
        o[ni] = __builtin_amdgcn_mfma_f32_16x16x32_bf16(pa, bv, o[ni], 0, 0, 0);
      }
    }

#pragma unroll
    for (int r = 0; r < 4; r++) {
#pragma unroll
      for (int m = 1; m < 16; m <<= 1) lsum[r] += __shfl_xor(lsum[r], m, 64);
    }

#pragma unroll
    for (int r = 0; r < 4; r++) {
      int rowt = row0t + r;
      if (rowt < NTOK) {
        float inv = 1.0f / lsum[r];
        u16* op = out + ((size_t)winabs * NTOK + rowt) * CH + head * 64;
#pragma unroll
        for (int ni = 0; ni < 4; ni++) op[ni * 16 + l15] = f2b(o[ni][r] * inv);
      }
    }
  }
}

// ---------------------------------------------------------------------------
extern "C" void kernel_launch(void* const* d_in, const int* in_sizes, int n_in,
                              void* d_out, int out_size, void* d_ws, size_t ws_size,
                              hipStream_t stream) {
  const float* hidden = (const float*)d_in[0];
  const float* ln1_w  = (const float*)d_in[1];
  const float* ln1_b  = (const float*)d_in[2];
  const float* qkv_w  = (const float*)d_in[3];
  const float* qkv_b  = (const float*)d_in[4];
  const float* proj_w = (const float*)d_in[5];
  const float* proj_b = (const float*)d_in[6];
  const float* rel_h  = (const float*)d_in[7];
  const float* rel_w  = (const float*)d_in[8];
  const float* ln2_w  = (const float*)d_in[9];
  const float* ln2_b  = (const float*)d_in[10];
  const float* fc1_w  = (const float*)d_in[11];
  const float* fc1_b  = (const float*)d_in[12];
  const float* fc2_w  = (const float*)d_in[13];
  const float* fc2_b  = (const float*)d_in[14];
  float* out = (float*)d_out;

  char* ws = (char*)d_ws;
  float* x_nhwc = (float*)ws;
  u16*   R1     = (u16*)(ws + 50331648);
  u16*   qkvT   = (u16*)(ws + 80437248);
  u16*   projT  = qkvT + (size_t)2304 * 768;
  u16*   fc1T   = projT + (size_t)768 * 768;
  u16*   fc2T   = fc1T + (size_t)3072 * 768;
  u16*   R2     = fc2T + (size_t)768 * 3072;
  size_t used   = (size_t)80437248 + 14155776;
  size_t r2e    = ws_size > used ? (ws_size - used) >> 1 : 0;  // bf16 elems

  const size_t PW_QKV = (size_t)NTOK * 3 * CH;            // 451584
  const size_t PW_VT  = (size_t)NHEAD * 64 * VSTR;        // 165888
  const size_t PW_RB  = (size_t)NHEAD * NTOK * 16;        // 37632 (x2 tables)
  const size_t perwin = PW_QKV + PW_VT + 2 * PW_RB;       // 692736 elems
  size_t wc_s = r2e / perwin;
  int Wc = wc_s >= NWINS ? NWINS : (int)wc_s;
  if (Wc < 1) Wc = 1;
  size_t rc_s = (r2e / MLPC / 128) * 128;
  int Rc = rc_s >= MREAL ? MREAL : (int)rc_s;
  if (Rc < 128) Rc = 128;

  u16* Vt  = R2 + (size_t)Wc * PW_QKV;
  u16* rhg = Vt + (size_t)Wc * PW_VT;
  u16* rwg = rhg + (size_t)Wc * PW_RB;

  // 0) weight convert + transpose
  k_wt<<<dim3(72, 24), dim3(32, 8), 0, stream>>>(qkv_w, qkvT, CH, 3 * CH);
  k_wt<<<dim3(24, 24), dim3(32, 8), 0, stream>>>(proj_w, projT, CH, CH);
  k_wt<<<dim3(96, 24), dim3(32, 8), 0, stream>>>(fc1_w, fc1T, CH, MLPC);
  k_wt<<<dim3(24, 96), dim3(32, 8), 0, stream>>>(fc2_w, fc2T, MLPC, CH);

  hipMemsetAsync(R1, 0, (size_t)MWIN * CH * sizeof(u16), stream);

  // 1) NCHW -> NHWC
  k_nchw2nhwc<<<dim3(128, 24, NIMG), dim3(32, 8), 0, stream>>>(hidden, x_nhwc);
  // 2) LN1 -> window-partitioned xln (wave-per-row)
  k_ln<<<MREAL / 4, 256, 0, stream>>>(x_nhwc, ln1_w, ln1_b, R1, 1);
  // 3+4) per window chunk: qkv GEMM -> rel bias -> attn
  for (int w0 = 0; w0 < NWINS; w0 += Wc) {
    int wc = NWINS - w0 < Wc ? NWINS - w0 : Wc;
    int Mc = wc * NTOK;
    k_gemm_mfma<<<dim3(18, (Mc + 127) / 128), 256, 0, stream>>>(
        R1 + (size_t)w0 * NTOK * CH, qkvT, qkv_b, R2, Vt,
        Mc, 3 * CH, CH, 0, 3, 0);
    k_relbias<<<(Mc * NHEAD + 255) / 256, 256, 0, stream>>>(
        R2, rel_h, rel_w, rhg, rwg, Mc);
    k_attn_mfma<<<dim3(NHEAD, wc), 256, 0, stream>>>(
        R2, Vt, rhg, rwg, R1, w0);
  }
  // 5) proj + window-unpartition residual add
  k_gemm_mfma<<<dim3(6, (MWIN + 127) / 128), 256, 0, stream>>>(
      R1, projT, proj_b, x_nhwc, nullptr, MWIN, CH, CH, 0, 2, 0);
  // 6) LN2 (wave-per-row)
  k_ln<<<MREAL / 4, 256, 0, stream>>>(x_nhwc, ln2_w, ln2_b, R1, 0);
  // 7+8) fc1+GELU -> fc2 + residual add
  for (int r0 = 0; r0 < MREAL; r0 += Rc) {
    int rc = MREAL - r0 < Rc ? MREAL - r0 : Rc;
    k_gemm_mfma<<<dim3(24, (rc + 127) / 128), 256, 0, stream>>>(
        R1 + (size_t)r0 * CH, fc1T, fc1_b, R2, nullptr, rc, MLPC, CH, 1, 0, 0);
    k_gemm_mfma<<<dim3(6, (rc + 127) / 128), 256, 0, stream>>>(
        R2, fc2T, fc2_b, x_nhwc + (size_t)r0 * CH, nullptr, rc, CH, MLPC, 0, 1, 0);
  }
  // 9) NHWC -> NCHW output
  k_nhwc2nchw<<<dim3(128, 24, NIMG), dim3(32, 8), 0, stream>>>(x_nhwc, out);
}